// Round 1
// baseline (284.816 us; speedup 1.0000x reference)
//
#include <hip/hip_runtime.h>
#include <stdint.h>

#define NTHREADS 256
#define RPB 64        // rows per block
#define TPR 4         // threads per row
#define KDIM 64
#define LD 65         // padded leading dim for xS (2-way bank alias = free)

// LDS budget: 16640 + 16384 + 256 + 8192 + 8192 + 2048 + 8192 + 4096 = 64000 B <= 64 KB
__global__ __launch_bounds__(NTHREADS, 2)
void poly_kernel(const float* __restrict__ x, const int* __restrict__ S,
                 const float* __restrict__ a, const float* __restrict__ b,
                 const int* __restrict__ idx3, const float* __restrict__ c3,
                 const int* __restrict__ idx4, const float* __restrict__ c4,
                 const int* __restrict__ idx5, const float* __restrict__ c5,
                 float* __restrict__ out)
{
    __shared__ float xS[KDIM * LD];     // xS[k][row], transposed, padded
    __shared__ float bS[KDIM * KDIM];
    __shared__ float aS[KDIM];
    __shared__ uint4 p3[512];           // {off0, off1, off2, bits(c3)}
    __shared__ uint4 p4[512];           // {off0..off3}
    __shared__ float c4s[512];
    __shared__ uint4 p5[512];           // {off0..off3}
    __shared__ uint2 p5b[512];          // {off4, bits(c5)}

    const int tid  = threadIdx.x;
    const int row0 = blockIdx.x * RPB;

    // ---- stage b (coalesced float4: 4096 floats / 256 threads = 4 x float4) ----
    {
        const float4* bin = (const float4*)b;
        float4* bsh = (float4*)bS;
        #pragma unroll
        for (int m = 0; m < 4; ++m) bsh[tid + m * NTHREADS] = bin[tid + m * NTHREADS];
    }
    if (tid < KDIM) aS[tid] = a[tid];

    // ---- prepack monomial tables: idx -> prescaled byte offset idx*LD*4 = idx*260 ----
    #pragma unroll
    for (int t = tid; t < 512; t += NTHREADS) {
        uint4 p;
        p.x = (unsigned)idx3[t * 3 + 0] * 260u;
        p.y = (unsigned)idx3[t * 3 + 1] * 260u;
        p.z = (unsigned)idx3[t * 3 + 2] * 260u;
        p.w = __float_as_uint(c3[t]);
        p3[t] = p;
    }
    #pragma unroll
    for (int t = tid; t < 512; t += NTHREADS) {
        uint4 p;
        p.x = (unsigned)idx4[t * 4 + 0] * 260u;
        p.y = (unsigned)idx4[t * 4 + 1] * 260u;
        p.z = (unsigned)idx4[t * 4 + 2] * 260u;
        p.w = (unsigned)idx4[t * 4 + 3] * 260u;
        p4[t] = p;
        c4s[t] = c4[t];
    }
    #pragma unroll
    for (int t = tid; t < 512; t += NTHREADS) {
        uint4 p;
        p.x = (unsigned)idx5[t * 5 + 0] * 260u;
        p.y = (unsigned)idx5[t * 5 + 1] * 260u;
        p.z = (unsigned)idx5[t * 5 + 2] * 260u;
        p.w = (unsigned)idx5[t * 5 + 3] * 260u;
        p5[t] = p;
        p5b[t] = make_uint2((unsigned)idx5[t * 5 + 4] * 260u, __float_as_uint(c5[t]));
    }

    // ---- gather: each wave-iteration gathers one row's 64 scattered columns ----
    {
        const int k  = tid & 63;          // invariant across iters
        const int sk = S[k];              // L1-cached, hoisted
        #pragma unroll
        for (int m = 0; m < (RPB * KDIM) / NTHREADS; ++m) {   // 16 iters
            int e  = tid + m * NTHREADS;
            int lr = e >> 6;              // local row
            xS[k * LD + lr] = x[(size_t)(row0 + lr) * 1024 + sk];
        }
    }
    __syncthreads();

    // ---- compute: 4 threads per row ----
    const int lr   = tid >> 2;            // 0..63
    const int role = tid & 3;
    const char* xbase = (const char*)xS + (lr << 2);

    // cache this row's 64 values in VGPRs (static indices only below)
    float xv[64];
    #pragma unroll
    for (int i = 0; i < 64; ++i) xv[i] = xS[i * LD + lr];

    float acc = 0.f;

    // lin + quad: this thread handles all j == 4*jj + role
    #pragma unroll
    for (int jj = 0; jj < 16; ++jj) {
        const int j = 4 * jj + role;
        float xj = xS[j * LD + lr];       // dynamic j -> one LDS read
        float s  = aS[j];                 // folds lin term in
        #pragma unroll
        for (int i = 0; i < 4 * jj; ++i)  // static trip count
            s += bS[i * KDIM + j] * xv[i];
        #pragma unroll
        for (int m = 0; m < 3; ++m) {     // predicated remainder: i = 4jj+m < j iff m < role
            float t = bS[(4 * jj + m) * KDIM + j] * xv[4 * jj + m];
            s += (m < role) ? t : 0.f;
        }
        acc += s * xj;
    }

    // monomials: terms split by t == role (mod 4)
    float acc2 = 0.f;
    #pragma unroll 4
    for (int t = role; t < 512; t += 4) {
        uint4 p = p3[t];
        float v0 = *(const float*)(xbase + p.x);
        float v1 = *(const float*)(xbase + p.y);
        float v2 = *(const float*)(xbase + p.z);
        acc2 += __uint_as_float(p.w) * ((v0 * v1) * v2);
    }
    #pragma unroll 4
    for (int t = role; t < 512; t += 4) {
        uint4 p = p4[t];
        float v0 = *(const float*)(xbase + p.x);
        float v1 = *(const float*)(xbase + p.y);
        float v2 = *(const float*)(xbase + p.z);
        float v3 = *(const float*)(xbase + p.w);
        acc2 += c4s[t] * ((v0 * v1) * (v2 * v3));
    }
    #pragma unroll 4
    for (int t = role; t < 512; t += 4) {
        uint4 p = p5[t];
        uint2 q = p5b[t];
        float v0 = *(const float*)(xbase + p.x);
        float v1 = *(const float*)(xbase + p.y);
        float v2 = *(const float*)(xbase + p.z);
        float v3 = *(const float*)(xbase + p.w);
        float v4 = *(const float*)(xbase + q.x);
        acc2 += __uint_as_float(q.y) * (((v0 * v1) * (v2 * v3)) * v4);
    }
    acc += acc2;

    // combine 4 role-partials (lanes 4r..4r+3 are consecutive)
    acc += __shfl_xor(acc, 1, 64);
    acc += __shfl_xor(acc, 2, 64);
    if (role == 0) out[row0 + lr] = acc;
}

extern "C" void kernel_launch(void* const* d_in, const int* in_sizes, int n_in,
                              void* d_out, int out_size, void* d_ws, size_t ws_size,
                              hipStream_t stream) {
    const float* x  = (const float*)d_in[0];
    const int*   S  = (const int*)d_in[1];
    const float* a  = (const float*)d_in[2];
    const float* b  = (const float*)d_in[3];
    const int*   i3 = (const int*)d_in[4];
    const float* c3 = (const float*)d_in[5];
    const int*   i4 = (const int*)d_in[6];
    const float* c4 = (const float*)d_in[7];
    const int*   i5 = (const int*)d_in[8];
    const float* c5 = (const float*)d_in[9];
    float* out = (float*)d_out;

    dim3 grid(32768 / RPB);   // 512 blocks
    poly_kernel<<<grid, NTHREADS, 0, stream>>>(x, S, a, b, i3, c3, i4, c4, i5, c5, out);
}

// Round 2
// 236.772 us; speedup vs baseline: 1.2029x; 1.2029x over previous
//
#include <hip/hip_runtime.h>
#include <stdint.h>

#define NT 256
#define RPB 64
#define XSTR_B 272        // byte stride between k-slots of xS (68 floats, 17 chunks -> odd, conflict-friendly)

// ws layout (byte offsets), total 47104 B
#define WS_BU   0         // 4096 floats: triu(b,1), zeros elsewhere
#define WS_P3   16384     // 512 x uint4 {off0,off1,off2,bits(c3)}
#define WS_P4   24576     // 512 x uint4 {off0..off3}
#define WS_C4   32768     // 512 x float
#define WS_P5   34816     // 512 x uint4 {off0..off3}
#define WS_P5B  43008     // 512 x uint2 {off4, bits(c5)}

static __device__ __forceinline__ float4 f4fma(float s, float4 v, float4 acc) {
    acc.x += s * v.x; acc.y += s * v.y; acc.z += s * v.z; acc.w += s * v.w;
    return acc;
}

__global__ void prepack_kernel(const float* __restrict__ b,
                               const int* __restrict__ i3, const float* __restrict__ c3,
                               const int* __restrict__ i4, const float* __restrict__ c4,
                               const int* __restrict__ i5, const float* __restrict__ c5,
                               unsigned char* __restrict__ ws)
{
    const int g = blockIdx.x * NT + threadIdx.x;
    const int stride = gridDim.x * NT;
    float* bu  = (float*)(ws + WS_BU);
    uint4* p3  = (uint4*)(ws + WS_P3);
    uint4* p4  = (uint4*)(ws + WS_P4);
    float* c4o = (float*)(ws + WS_C4);
    uint4* p5  = (uint4*)(ws + WS_P5);
    uint2* p5b = (uint2*)(ws + WS_P5B);

    for (int e = g; e < 4096; e += stride) {
        int i = e >> 6, j = e & 63;
        bu[e] = (i < j) ? b[e] : 0.0f;
    }
    for (int t = g; t < 512; t += stride) {
        p3[t] = make_uint4((unsigned)i3[3*t+0] * XSTR_B, (unsigned)i3[3*t+1] * XSTR_B,
                           (unsigned)i3[3*t+2] * XSTR_B, __float_as_uint(c3[t]));
        p4[t] = make_uint4((unsigned)i4[4*t+0] * XSTR_B, (unsigned)i4[4*t+1] * XSTR_B,
                           (unsigned)i4[4*t+2] * XSTR_B, (unsigned)i4[4*t+3] * XSTR_B);
        c4o[t] = c4[t];
        p5[t] = make_uint4((unsigned)i5[5*t+0] * XSTR_B, (unsigned)i5[5*t+1] * XSTR_B,
                           (unsigned)i5[5*t+2] * XSTR_B, (unsigned)i5[5*t+3] * XSTR_B);
        p5b[t] = make_uint2((unsigned)i5[5*t+4] * XSTR_B, __float_as_uint(c5[t]));
    }
}

// LDS: 17408 + 16384 + 256 + 2048 + 128 + 4096 = 40320 B  -> 2+ blocks/CU
__global__ __launch_bounds__(NT, 2)
void poly_main(const float* __restrict__ x, const int* __restrict__ S,
               const float* __restrict__ a,
               const unsigned char* __restrict__ ws,
               float* __restrict__ out)
{
    __shared__ float xS[64 * 68];       // xS[k][row], 68-float stride
    __shared__ float bS[64 * 64];       // triu(b,1) with zeros at i>=j
    __shared__ float aS[64];
    __shared__ short slot[1024];        // column -> k (run leader), else -1
    __shared__ short lead[64];          // k -> leader of its duplicate run
    __shared__ float red[1024];         // [ts][row] partial sums

    const int tid  = threadIdx.x;
    const int row0 = blockIdx.x * RPB;

    // ---- init slot table + stage bu into LDS (coalesced) ----
    ((short4*)slot)[tid] = make_short4(-1, -1, -1, -1);
    {
        const float4* bin = (const float4*)(ws + WS_BU);
        float4* bsh = (float4*)bS;
        #pragma unroll
        for (int m = 0; m < 4; ++m) bsh[tid + m * NT] = bin[tid + m * NT];
    }
    if (tid < 64) aS[tid] = a[tid];
    __syncthreads();
    if (tid < 64) {
        int sv = S[tid];
        int k0 = tid;
        while (k0 > 0 && S[k0 - 1] == sv) --k0;   // duplicate-run leader
        lead[tid] = (short)k0;
        if (k0 == tid) slot[sv] = (short)tid;     // unique writer per column
    }
    __syncthreads();

    // ---- stream whole rows of x (perfectly coalesced), select into LDS ----
    {
        short4 sl = ((short4*)slot)[tid];         // my 4 columns' dest slots
        int o0 = (int)sl.x * XSTR_B;
        int o1 = (int)sl.y * XSTR_B;
        int o2 = (int)sl.z * XSTR_B;
        int o3 = (int)sl.w * XSTR_B;
        const float4* Xrow = (const float4*)(x + (size_t)row0 * 1024);
        char* xsb = (char*)xS;
        #pragma unroll 4
        for (int r = 0; r < RPB; ++r) {
            float4 v = Xrow[r * 256 + tid];
            int rb = r * 4;
            if (sl.x >= 0) *(float*)(xsb + o0 + rb) = v.x;
            if (sl.y >= 0) *(float*)(xsb + o1 + rb) = v.y;
            if (sl.z >= 0) *(float*)(xsb + o2 + rb) = v.z;
            if (sl.w >= 0) *(float*)(xsb + o3 + rb) = v.w;
        }
    }
    __syncthreads();

    // ---- replicate duplicated columns (S can repeat): k gets copy of its leader ----
    {
        int k = tid >> 2, q = tid & 3;
        int k0 = lead[k];
        if (k0 != k) {
            float4* dst = (float4*)((char*)xS + k  * XSTR_B) + q * 4;
            const float4* src = (const float4*)((char*)xS + k0 * XSTR_B) + q * 4;
            #pragma unroll
            for (int m = 0; m < 4; ++m) dst[m] = src[m];
        }
    }
    __syncthreads();

    // ---- compute: thread = (rg, ts); rg owns rows 4rg..4rg+3 (float4), ts = work slice ----
    const int rg = tid & 15;
    const int ts = tid >> 4;
    const char* xb = (const char*)xS + rg * 16;

    // lin + quad: j = jj*16 + ts; d_jj = sum_i bu[i][j] * x_i  (bu zero at i>=j)
    float4 d0 = make_float4(0.f, 0.f, 0.f, 0.f);
    float4 d1 = d0, d2 = d0, d3 = d0;
    #pragma unroll 8
    for (int i = 0; i < 64; ++i) {
        float4 xi = *(const float4*)(xb + i * XSTR_B);
        float b0 = bS[i * 64 + ts];
        float b1 = bS[i * 64 + ts + 16];
        float b2 = bS[i * 64 + ts + 32];
        float b3 = bS[i * 64 + ts + 48];
        d0 = f4fma(b0, xi, d0);
        d1 = f4fma(b1, xi, d1);
        d2 = f4fma(b2, xi, d2);
        d3 = f4fma(b3, xi, d3);
    }
    float4 xj0 = *(const float4*)(xb + (ts +  0) * XSTR_B);
    float4 xj1 = *(const float4*)(xb + (ts + 16) * XSTR_B);
    float4 xj2 = *(const float4*)(xb + (ts + 32) * XSTR_B);
    float4 xj3 = *(const float4*)(xb + (ts + 48) * XSTR_B);
    float a0 = aS[ts], a1 = aS[ts + 16], a2 = aS[ts + 32], a3 = aS[ts + 48];

    float4 acc;
    acc.x = (a0 + d0.x) * xj0.x + (a1 + d1.x) * xj1.x + (a2 + d2.x) * xj2.x + (a3 + d3.x) * xj3.x;
    acc.y = (a0 + d0.y) * xj0.y + (a1 + d1.y) * xj1.y + (a2 + d2.y) * xj2.y + (a3 + d3.y) * xj3.y;
    acc.z = (a0 + d0.z) * xj0.z + (a1 + d1.z) * xj1.z + (a2 + d2.z) * xj2.z + (a3 + d3.z) * xj3.z;
    acc.w = (a0 + d0.w) * xj0.w + (a1 + d1.w) * xj1.w + (a2 + d2.w) * xj2.w + (a3 + d3.w) * xj3.w;

    // ---- monomials: term t = 16*m + ts; tables from global (L1-resident) ----
    const uint4* p3g  = (const uint4*)(ws + WS_P3);
    const uint4* p4g  = (const uint4*)(ws + WS_P4);
    const float* c4g  = (const float*)(ws + WS_C4);
    const uint4* p5g  = (const uint4*)(ws + WS_P5);
    const uint2* p5bg = (const uint2*)(ws + WS_P5B);

    #pragma unroll 2
    for (int m = 0; m < 32; ++m) {
        uint4 p = p3g[16 * m + ts];
        float4 v0 = *(const float4*)(xb + p.x);
        float4 v1 = *(const float4*)(xb + p.y);
        float4 v2 = *(const float4*)(xb + p.z);
        float c = __uint_as_float(p.w);
        acc.x += c * (v0.x * v1.x * v2.x);
        acc.y += c * (v0.y * v1.y * v2.y);
        acc.z += c * (v0.z * v1.z * v2.z);
        acc.w += c * (v0.w * v1.w * v2.w);
    }
    #pragma unroll 2
    for (int m = 0; m < 32; ++m) {
        uint4 p = p4g[16 * m + ts];
        float c = c4g[16 * m + ts];
        float4 v0 = *(const float4*)(xb + p.x);
        float4 v1 = *(const float4*)(xb + p.y);
        float4 v2 = *(const float4*)(xb + p.z);
        float4 v3 = *(const float4*)(xb + p.w);
        acc.x += c * ((v0.x * v1.x) * (v2.x * v3.x));
        acc.y += c * ((v0.y * v1.y) * (v2.y * v3.y));
        acc.z += c * ((v0.z * v1.z) * (v2.z * v3.z));
        acc.w += c * ((v0.w * v1.w) * (v2.w * v3.w));
    }
    #pragma unroll 2
    for (int m = 0; m < 32; ++m) {
        uint4 p = p5g[16 * m + ts];
        uint2 q = p5bg[16 * m + ts];
        float4 v0 = *(const float4*)(xb + p.x);
        float4 v1 = *(const float4*)(xb + p.y);
        float4 v2 = *(const float4*)(xb + p.z);
        float4 v3 = *(const float4*)(xb + p.w);
        float4 v4 = *(const float4*)(xb + q.x);
        float c = __uint_as_float(q.y);
        acc.x += c * (((v0.x * v1.x) * (v2.x * v3.x)) * v4.x);
        acc.y += c * (((v0.y * v1.y) * (v2.y * v3.y)) * v4.y);
        acc.z += c * (((v0.z * v1.z) * (v2.z * v3.z)) * v4.z);
        acc.w += c * (((v0.w * v1.w) * (v2.w * v3.w)) * v4.w);
    }

    // ---- reduce 16 ts-partials per row, store ----
    ((float4*)red)[ts * 16 + rg] = acc;
    __syncthreads();
    if (tid < 64) {
        float s = 0.f;
        #pragma unroll
        for (int t = 0; t < 16; ++t) s += red[t * 64 + tid];
        out[row0 + tid] = s;
    }
}

extern "C" void kernel_launch(void* const* d_in, const int* in_sizes, int n_in,
                              void* d_out, int out_size, void* d_ws, size_t ws_size,
                              hipStream_t stream) {
    const float* x  = (const float*)d_in[0];
    const int*   S  = (const int*)d_in[1];
    const float* a  = (const float*)d_in[2];
    const float* b  = (const float*)d_in[3];
    const int*   i3 = (const int*)d_in[4];
    const float* c3 = (const float*)d_in[5];
    const int*   i4 = (const int*)d_in[6];
    const float* c4 = (const float*)d_in[7];
    const int*   i5 = (const int*)d_in[8];
    const float* c5 = (const float*)d_in[9];
    unsigned char* ws = (unsigned char*)d_ws;
    float* out = (float*)d_out;

    prepack_kernel<<<16, NT, 0, stream>>>(b, i3, c3, i4, c4, i5, c5, ws);
    poly_main<<<32768 / RPB, NT, 0, stream>>>(x, S, a, ws, out);
}

// Round 3
// 218.806 us; speedup vs baseline: 1.3017x; 1.0821x over previous
//
#include <hip/hip_runtime.h>
#include <stdint.h>

#define NT 512
#define RPB 64
#define XSTR_B 272        // byte stride between k-slots of xS (68 floats)

// ws layout (byte offsets), total 47104 B
#define WS_BU2  0         // 2048 float2: {triu(b,1)[i][j], triu(b,1)[i][j+32]} for j in [0,32)
#define WS_P3   16384     // 512 x uint4 {off0,off1,off2,bits(c3)}
#define WS_P4   24576     // 512 x uint4 {off0..off3}
#define WS_C4   32768     // 512 x float
#define WS_P5   34816     // 512 x uint4 {off0..off3}
#define WS_P5B  43008     // 512 x uint2 {off4, bits(c5)}

static __device__ __forceinline__ float4 f4fma(float s, float4 v, float4 acc) {
    acc.x += s * v.x; acc.y += s * v.y; acc.z += s * v.z; acc.w += s * v.w;
    return acc;
}

__global__ void prepack_kernel(const float* __restrict__ b,
                               const int* __restrict__ i3, const float* __restrict__ c3,
                               const int* __restrict__ i4, const float* __restrict__ c4,
                               const int* __restrict__ i5, const float* __restrict__ c5,
                               unsigned char* __restrict__ ws)
{
    const int g = blockIdx.x * 256 + threadIdx.x;
    const int stride = gridDim.x * 256;
    float2* bu2 = (float2*)(ws + WS_BU2);
    uint4* p3  = (uint4*)(ws + WS_P3);
    uint4* p4  = (uint4*)(ws + WS_P4);
    float* c4o = (float*)(ws + WS_C4);
    uint4* p5  = (uint4*)(ws + WS_P5);
    uint2* p5b = (uint2*)(ws + WS_P5B);

    for (int e = g; e < 2048; e += stride) {
        int i = e >> 5, j = e & 31;
        float lo = (i < j)      ? b[i * 64 + j]      : 0.0f;
        float hi = (i < j + 32) ? b[i * 64 + j + 32] : 0.0f;
        bu2[e] = make_float2(lo, hi);
    }
    for (int t = g; t < 512; t += stride) {
        p3[t] = make_uint4((unsigned)i3[3*t+0] * XSTR_B, (unsigned)i3[3*t+1] * XSTR_B,
                           (unsigned)i3[3*t+2] * XSTR_B, __float_as_uint(c3[t]));
        p4[t] = make_uint4((unsigned)i4[4*t+0] * XSTR_B, (unsigned)i4[4*t+1] * XSTR_B,
                           (unsigned)i4[4*t+2] * XSTR_B, (unsigned)i4[4*t+3] * XSTR_B);
        c4o[t] = c4[t];
        p5[t] = make_uint4((unsigned)i5[5*t+0] * XSTR_B, (unsigned)i5[5*t+1] * XSTR_B,
                           (unsigned)i5[5*t+2] * XSTR_B, (unsigned)i5[5*t+3] * XSTR_B);
        p5b[t] = make_uint2((unsigned)i5[5*t+4] * XSTR_B, __float_as_uint(c5[t]));
    }
}

// LDS: 17408 + 16384 + 256 + 2048 + 128 + 8192 = 44416 B -> 2 blocks/CU, 16 waves/CU
__global__ __launch_bounds__(NT, 4)
void poly_main(const float* __restrict__ x, const int* __restrict__ S,
               const float* __restrict__ a,
               const unsigned char* __restrict__ ws,
               float* __restrict__ out)
{
    __shared__ float  xS[64 * 68];      // xS[k][row], 68-float stride
    __shared__ float2 buS[64 * 32];     // {bu[i][ts], bu[i][ts+32]}
    __shared__ float  aS[64];
    __shared__ short  slot[1024];       // column -> k (run leader), else -1
    __shared__ short  lead[64];         // k -> leader of its duplicate run
    __shared__ float  red[32 * 64];     // [ts][row] partial sums

    const int tid  = threadIdx.x;
    const int row0 = blockIdx.x * RPB;

    // ---- init slot table, stage bu2 + a into LDS (coalesced) ----
    if (tid < 256) ((short4*)slot)[tid] = make_short4(-1, -1, -1, -1);
    {
        const float4* bin = (const float4*)(ws + WS_BU2);
        float4* bsh = (float4*)buS;
        bsh[tid]       = bin[tid];
        bsh[tid + 512] = bin[tid + 512];
    }
    if (tid < 64) aS[tid] = a[tid];
    __syncthreads();
    if (tid < 64) {
        int sv = S[tid];
        int k0 = tid;
        while (k0 > 0 && S[k0 - 1] == sv) --k0;   // duplicate-run leader
        lead[tid] = (short)k0;
        if (k0 == tid) slot[sv] = (short)tid;     // unique writer per column
    }
    __syncthreads();

    // ---- stream x rows (coalesced), select into LDS; skip dead col4 groups ----
    {
        const int col4 = tid & 255;
        const int r0   = tid >> 8;                // 0 or 1
        short4 sl = ((short4*)slot)[col4];
        short mx = max(max(sl.x, sl.y), max(sl.z, sl.w));
        if (mx >= 0) {
            int o0 = (int)sl.x * XSTR_B;
            int o1 = (int)sl.y * XSTR_B;
            int o2 = (int)sl.z * XSTR_B;
            int o3 = (int)sl.w * XSTR_B;
            const float4* Xrow = (const float4*)(x + (size_t)row0 * 1024);
            char* xsb = (char*)xS;
            #pragma unroll 4
            for (int it = 0; it < 32; ++it) {
                int r = r0 + it * 2;
                float4 v = Xrow[r * 256 + col4];
                int rb = r * 4;
                if (sl.x >= 0) *(float*)(xsb + o0 + rb) = v.x;
                if (sl.y >= 0) *(float*)(xsb + o1 + rb) = v.y;
                if (sl.z >= 0) *(float*)(xsb + o2 + rb) = v.z;
                if (sl.w >= 0) *(float*)(xsb + o3 + rb) = v.w;
            }
        }
    }
    __syncthreads();

    // ---- replicate duplicated columns: k gets copy of its run leader ----
    if (tid < 256) {
        int k = tid >> 2, q = tid & 3;
        int k0 = lead[k];
        if (k0 != k) {
            float4* dst = (float4*)((char*)xS + k  * XSTR_B) + q * 4;
            const float4* src = (const float4*)((char*)xS + k0 * XSTR_B) + q * 4;
            #pragma unroll
            for (int m = 0; m < 4; ++m) dst[m] = src[m];
        }
    }
    __syncthreads();

    // ---- compute: rg owns rows 4rg..4rg+3 (float4), ts = work slice (32 slices) ----
    const int rg = tid & 15;
    const int ts = tid >> 4;
    const char* xb = (const char*)xS + rg * 16;

    // lin + quad: j0 = ts, j1 = ts+32
    float4 d0 = make_float4(0.f, 0.f, 0.f, 0.f);
    float4 d1 = d0;
    #pragma unroll 8
    for (int i = 0; i < 64; ++i) {
        float4 xi = *(const float4*)(xb + i * XSTR_B);
        float2 bb = buS[i * 32 + ts];
        d0 = f4fma(bb.x, xi, d0);
        d1 = f4fma(bb.y, xi, d1);
    }
    float4 xj0 = *(const float4*)(xb + ts * XSTR_B);
    float4 xj1 = *(const float4*)(xb + (ts + 32) * XSTR_B);
    float a0 = aS[ts], a1 = aS[ts + 32];

    float4 acc;
    acc.x = (a0 + d0.x) * xj0.x + (a1 + d1.x) * xj1.x;
    acc.y = (a0 + d0.y) * xj0.y + (a1 + d1.y) * xj1.y;
    acc.z = (a0 + d0.z) * xj0.z + (a1 + d1.z) * xj1.z;
    acc.w = (a0 + d0.w) * xj0.w + (a1 + d1.w) * xj1.w;

    // ---- monomials: term t = 32*m + ts; tables from global (L1-resident) ----
    const uint4* p3g  = (const uint4*)(ws + WS_P3);
    const uint4* p4g  = (const uint4*)(ws + WS_P4);
    const float* c4g  = (const float*)(ws + WS_C4);
    const uint4* p5g  = (const uint4*)(ws + WS_P5);
    const uint2* p5bg = (const uint2*)(ws + WS_P5B);

    #pragma unroll 4
    for (int m = 0; m < 16; ++m) {
        uint4 p = p3g[32 * m + ts];
        float4 v0 = *(const float4*)(xb + p.x);
        float4 v1 = *(const float4*)(xb + p.y);
        float4 v2 = *(const float4*)(xb + p.z);
        float c = __uint_as_float(p.w);
        acc.x += c * (v0.x * v1.x * v2.x);
        acc.y += c * (v0.y * v1.y * v2.y);
        acc.z += c * (v0.z * v1.z * v2.z);
        acc.w += c * (v0.w * v1.w * v2.w);
    }
    #pragma unroll 4
    for (int m = 0; m < 16; ++m) {
        uint4 p = p4g[32 * m + ts];
        float c = c4g[32 * m + ts];
        float4 v0 = *(const float4*)(xb + p.x);
        float4 v1 = *(const float4*)(xb + p.y);
        float4 v2 = *(const float4*)(xb + p.z);
        float4 v3 = *(const float4*)(xb + p.w);
        acc.x += c * ((v0.x * v1.x) * (v2.x * v3.x));
        acc.y += c * ((v0.y * v1.y) * (v2.y * v3.y));
        acc.z += c * ((v0.z * v1.z) * (v2.z * v3.z));
        acc.w += c * ((v0.w * v1.w) * (v2.w * v3.w));
    }
    #pragma unroll 4
    for (int m = 0; m < 16; ++m) {
        uint4 p = p5g[32 * m + ts];
        uint2 q = p5bg[32 * m + ts];
        float4 v0 = *(const float4*)(xb + p.x);
        float4 v1 = *(const float4*)(xb + p.y);
        float4 v2 = *(const float4*)(xb + p.z);
        float4 v3 = *(const float4*)(xb + p.w);
        float4 v4 = *(const float4*)(xb + q.x);
        float c = __uint_as_float(q.y);
        acc.x += c * (((v0.x * v1.x) * (v2.x * v3.x)) * v4.x);
        acc.y += c * (((v0.y * v1.y) * (v2.y * v3.y)) * v4.y);
        acc.z += c * (((v0.z * v1.z) * (v2.z * v3.z)) * v4.z);
        acc.w += c * (((v0.w * v1.w) * (v2.w * v3.w)) * v4.w);
    }

    // ---- reduce 32 ts-partials per row, store ----
    ((float4*)red)[ts * 16 + rg] = acc;
    __syncthreads();
    if (tid < 64) {
        float s = 0.f;
        #pragma unroll
        for (int t = 0; t < 32; ++t) s += red[t * 64 + tid];
        out[row0 + tid] = s;
    }
}

extern "C" void kernel_launch(void* const* d_in, const int* in_sizes, int n_in,
                              void* d_out, int out_size, void* d_ws, size_t ws_size,
                              hipStream_t stream) {
    const float* x  = (const float*)d_in[0];
    const int*   S  = (const int*)d_in[1];
    const float* a  = (const float*)d_in[2];
    const float* b  = (const float*)d_in[3];
    const int*   i3 = (const int*)d_in[4];
    const float* c3 = (const float*)d_in[5];
    const int*   i4 = (const int*)d_in[6];
    const float* c4 = (const float*)d_in[7];
    const int*   i5 = (const int*)d_in[8];
    const float* c5 = (const float*)d_in[9];
    unsigned char* ws = (unsigned char*)d_ws;
    float* out = (float*)d_out;

    prepack_kernel<<<16, 256, 0, stream>>>(b, i3, c3, i4, c4, i5, c5, ws);
    poly_main<<<32768 / RPB, NT, 0, stream>>>(x, S, a, ws, out);
}